// Round 6
// baseline (453.419 us; speedup 1.0000x reference)
//
#include <hip/hip_runtime.h>
#include <hip/hip_bf16.h>

#define NN 50000
#define EE 800000
#define ET (EE + NN)
#define F_IN 128
#define HID 32
#define H1 4
#define H2 8
#define E_DEC 100000
#define NEG_SLOPE 0.2f

typedef __attribute__((ext_vector_type(8))) short short8;
typedef __attribute__((ext_vector_type(4))) float floatx4;

__device__ __forceinline__ unsigned short f2b(float f) {
    __hip_bfloat16 h = __float2bfloat16(f);
    return *reinterpret_cast<unsigned short*>(&h);
}
__device__ __forceinline__ float b2f(unsigned short u) {
    return __uint_as_float(((unsigned int)u) << 16);
}

// ---------------- zero ints ----------------
__global__ void fillint_k(int* __restrict__ p, int n) {
    int i = blockIdx.x * blockDim.x + threadIdx.x;
    if (i < n) p[i] = 0;
}

// ---------------- CSR build ----------------
__global__ void hist_k(const int* __restrict__ ei, int* __restrict__ counts) {
    int e = blockIdx.x * blockDim.x + threadIdx.x;
    if (e >= ET) return;
    int d = (e < EE) ? ei[EE + e] : e - EE;
    atomicAdd(&counts[d], 1);
}

__global__ void scan1_k(const int* __restrict__ counts, int* __restrict__ bsum) {
    __shared__ int sh[256];
    int t = threadIdx.x;
    int i = blockIdx.x * 256 + t;
    sh[t] = (i < NN) ? counts[i] : 0;
    __syncthreads();
    for (int off = 128; off > 0; off >>= 1) {
        if (t < off) sh[t] += sh[t + off];
        __syncthreads();
    }
    if (t == 0) bsum[blockIdx.x] = sh[0];
}

__global__ void scan2_k(int* __restrict__ bsum, int nb, int* __restrict__ start) {
    __shared__ int sh[256];
    int t = threadIdx.x;
    int v = (t < nb) ? bsum[t] : 0;
    sh[t] = v;
    __syncthreads();
    for (int off = 1; off < 256; off <<= 1) {
        int u = (t >= off) ? sh[t - off] : 0;
        __syncthreads();
        sh[t] += u;
        __syncthreads();
    }
    if (t < nb) bsum[t] = sh[t] - v;
    if (t == 0) start[NN] = ET;
}

__global__ void scan3_k(const int* __restrict__ counts, const int* __restrict__ bsum,
                        int* __restrict__ start, int* __restrict__ cursor) {
    __shared__ int sh[256];
    int t = threadIdx.x;
    int i = blockIdx.x * 256 + t;
    int c = (i < NN) ? counts[i] : 0;
    sh[t] = c;
    __syncthreads();
    for (int off = 1; off < 256; off <<= 1) {
        int u = (t >= off) ? sh[t - off] : 0;
        __syncthreads();
        sh[t] += u;
        __syncthreads();
    }
    int excl = sh[t] - c + bsum[blockIdx.x];
    if (i < NN) {
        start[i] = excl;
        cursor[i] = excl;
    }
}

__global__ void scatter_k(const int* __restrict__ ei, int* __restrict__ cursor,
                          int* __restrict__ csr) {
    int e = blockIdx.x * blockDim.x + threadIdx.x;
    if (e >= ET) return;
    int s, d;
    if (e < EE) { s = ei[e]; d = ei[EE + e]; } else { s = d = e - EE; }
    int slot = atomicAdd(&cursor[d], 1);
    csr[slot] = s;
}

// ---------------- fp32 -> bf16 convert (x) ----------------
__global__ void cvt_k(const float4* __restrict__ X, ushort4* __restrict__ Xb, int n4) {
    int i = blockIdx.x * blockDim.x + threadIdx.x;
    if (i >= n4) return;
    float4 v = X[i];
    ushort4 o;
    o.x = f2b(v.x);
    o.y = f2b(v.y);
    o.z = f2b(v.z);
    o.w = f2b(v.w);
    Xb[i] = o;
}

// ---------------- pack W into MFMA B-fragment layout ----------------
template <int OUT>
__global__ void packW_k(const float* __restrict__ W, unsigned short* __restrict__ Wp) {
    const int total = (OUT / 16) * 4 * 64;
    int id = blockIdx.x * 256 + threadIdx.x;
    if (id >= total) return;
    const int col = ((id >> 8) << 4) + (id & 15);
    const int k0 = ((id >> 6) & 3) * 32 + ((id >> 4) & 3) * 8;
    ushort4 lo, hi;
    lo.x = f2b(W[(k0 + 0) * OUT + col]);
    lo.y = f2b(W[(k0 + 1) * OUT + col]);
    lo.z = f2b(W[(k0 + 2) * OUT + col]);
    lo.w = f2b(W[(k0 + 3) * OUT + col]);
    hi.x = f2b(W[(k0 + 4) * OUT + col]);
    hi.y = f2b(W[(k0 + 5) * OUT + col]);
    hi.z = f2b(W[(k0 + 6) * OUT + col]);
    hi.w = f2b(W[(k0 + 7) * OUT + col]);
    ((ushort4*)Wp)[id * 2] = lo;
    ((ushort4*)Wp)[id * 2 + 1] = hi;
}

// ---------------- MFMA GEMM: H[M,OUT] = Xb[M,128] @ W, bf16 in/out, fp32 acc ------
template <int OUT, int CT>
__global__ void mfma_gemm_k(const unsigned short* __restrict__ Xb,
                            const unsigned short* __restrict__ Wp,
                            unsigned short* __restrict__ Hout) {
    const int wave = threadIdx.x >> 6;
    const int lane = threadIdx.x & 63;
    const int quad = lane >> 4;
    const int rl = lane & 15;
    const int r0 = blockIdx.x * 64;
    floatx4 acc[4][CT];
#pragma unroll
    for (int rt = 0; rt < 4; ++rt)
#pragma unroll
        for (int ct = 0; ct < CT; ++ct) acc[rt][ct] = {0.f, 0.f, 0.f, 0.f};

#pragma unroll
    for (int ks = 0; ks < 4; ++ks) {
        short8 a[4];
#pragma unroll
        for (int rt = 0; rt < 4; ++rt) {
            int row = r0 + rt * 16 + rl;
            row = row < NN ? row : NN - 1;
            a[rt] = *(const short8*)(Xb + (long long)row * 128 + ks * 32 + quad * 8);
        }
#pragma unroll
        for (int ct = 0; ct < CT; ++ct) {
            const int ctg = wave * CT + ct;
            const short8 b = *(const short8*)(Wp + (((ctg * 4 + ks) * 64 + lane) << 3));
#pragma unroll
            for (int rt = 0; rt < 4; ++rt)
                acc[rt][ct] = __builtin_amdgcn_mfma_f32_16x16x32_bf16(a[rt], b, acc[rt][ct], 0, 0, 0);
        }
    }
#pragma unroll
    for (int rt = 0; rt < 4; ++rt) {
        const int rowbase = r0 + rt * 16 + quad * 4;
#pragma unroll
        for (int ct = 0; ct < CT; ++ct) {
            const int col = (wave * CT + ct) * 16 + rl;
#pragma unroll
            for (int r = 0; r < 4; ++r) {
                const int row = rowbase + r;
                if (row < NN) Hout[(long long)row * OUT + col] = f2b(acc[rt][ct][r]);
            }
        }
    }
}

// ---------------- attention logit terms from h (bf16) ----------------
template <int OUT, int H>
__global__ void al_k(const unsigned short* __restrict__ Hb, const float* __restrict__ a_src,
                     const float* __restrict__ a_dst, float* __restrict__ als,
                     float* __restrict__ ald) {
    const int wave = threadIdx.x >> 6;
    const int lane = threadIdx.x & 63;
    const int row = blockIdx.x * 4 + wave;
    const int CPL = OUT / 64;
    const int G = 32 / CPL;
    const int c0 = lane * CPL;
    const int hd = c0 >> 5;
    float ps = 0.f, pd = 0.f;
#pragma unroll
    for (int j = 0; j < CPL; ++j) {
        const float hv = b2f(Hb[(long long)row * OUT + c0 + j]);
        const int cc = hd * 32 + ((c0 + j) & 31);
        ps += hv * a_src[cc];
        pd += hv * a_dst[cc];
    }
#pragma unroll
    for (int m = G / 2; m >= 1; m >>= 1) {
        ps += __shfl_xor(ps, m, 64);
        pd += __shfl_xor(pd, m, 64);
    }
    if ((lane & (G - 1)) == 0) {
        als[row * H + hd] = ps;
        ald[row * H + hd] = pd;
    }
}

// ---------------- CSR gather v2: ushort4/lane, 4 waves = 4*EPW edge slots ----------
// LPR lanes cover one row (4 channels each); slots reduce via shuffle + LDS.
template <int OUT, int H, bool RELU>
__global__ void gather_k(const int* __restrict__ start, const int* __restrict__ csr,
                         const float* __restrict__ als, const float* __restrict__ ald,
                         const unsigned short* __restrict__ Hin,
                         const float* __restrict__ bias, unsigned short* __restrict__ outp) {
    constexpr int LPR = OUT / 4;           // lanes per row: 64 (OUT=256) or 32 (OUT=128)
    constexpr int EPW = 64 / LPR;          // edge slots per wave: 1 or 2
    constexpr int SLOTS = 4 * EPW;
    constexpr int SHIFT = (EPW == 1) ? 6 : 5;
    const int d = blockIdx.x;
    const int t = threadIdx.x;
    const int wave = t >> 6;
    const int lane = t & 63;
    const int cl = lane & (LPR - 1);       // lane within row
    const int slot = wave * EPW + (lane >> SHIFT);
    const int hd = cl >> 3;                // (cl*4)>>5
    const int beg = start[d], end = start[d + 1];
    const float aldd = ald[d * H + hd];
    float a0 = 0.f, a1 = 0.f, a2 = 0.f, a3 = 0.f, den = 0.f;
    for (int i = beg + slot; i < end; i += SLOTS) {
        const int s = csr[i];
        float lg = als[s * H + hd] + aldd;
        lg = lg > 0.f ? lg : NEG_SLOPE * lg;
        const float w = __expf(lg);
        const ushort4 hv = *(const ushort4*)(Hin + (long long)s * OUT + cl * 4);
        den += w;
        a0 += w * b2f(hv.x);
        a1 += w * b2f(hv.y);
        a2 += w * b2f(hv.z);
        a3 += w * b2f(hv.w);
    }
    if (EPW == 2) {
        a0 += __shfl_xor(a0, 32, 64);
        a1 += __shfl_xor(a1, 32, 64);
        a2 += __shfl_xor(a2, 32, 64);
        a3 += __shfl_xor(a3, 32, 64);
        den += __shfl_xor(den, 32, 64);
    }
    __shared__ float sh[4][64][5];
    if (lane < LPR) {
        sh[wave][cl][0] = a0;
        sh[wave][cl][1] = a1;
        sh[wave][cl][2] = a2;
        sh[wave][cl][3] = a3;
        sh[wave][cl][4] = den;
    }
    __syncthreads();
    if (t < LPR) {
        float s0 = 0.f, s1 = 0.f, s2 = 0.f, s3 = 0.f, dn = 0.f;
#pragma unroll
        for (int w = 0; w < 4; ++w) {
            s0 += sh[w][t][0];
            s1 += sh[w][t][1];
            s2 += sh[w][t][2];
            s3 += sh[w][t][3];
            dn += sh[w][t][4];
        }
        const float inv = 1.f / (dn + 1e-16f);
        const int c0 = t * 4;
        float v0 = s0 * inv + bias[c0];
        float v1 = s1 * inv + bias[c0 + 1];
        float v2 = s2 * inv + bias[c0 + 2];
        float v3 = s3 * inv + bias[c0 + 3];
        if (RELU) {
            v0 = v0 > 0.f ? v0 : 0.f;
            v1 = v1 > 0.f ? v1 : 0.f;
            v2 = v2 > 0.f ? v2 : 0.f;
            v3 = v3 > 0.f ? v3 : 0.f;
        }
        ushort4 o;
        o.x = f2b(v0);
        o.y = f2b(v1);
        o.z = f2b(v2);
        o.w = f2b(v3);
        *(ushort4*)(outp + (long long)d * OUT + c0) = o;
    }
}

// ---------------- decode: logits = sum(z2[a]*z2[b]), z2 in bf16, ushort4/lane ------
__global__ void decode_k(const int* __restrict__ pei, const int* __restrict__ nei,
                         const unsigned short* __restrict__ z2, float* __restrict__ out) {
    const int w = threadIdx.x >> 6, lane = threadIdx.x & 63;
    const int idx = blockIdx.x * 4 + w;
    if (idx >= 2 * E_DEC) return;
    int a, b;
    if (idx < E_DEC) {
        a = pei[idx];
        b = pei[E_DEC + idx];
    } else {
        const int j = idx - E_DEC;
        a = nei[j];
        b = nei[E_DEC + j];
    }
    const ushort4 ua = *(const ushort4*)(z2 + (long long)a * 256 + lane * 4);
    const ushort4 ub = *(const ushort4*)(z2 + (long long)b * 256 + lane * 4);
    float s = b2f(ua.x) * b2f(ub.x) + b2f(ua.y) * b2f(ub.y) +
              b2f(ua.z) * b2f(ub.z) + b2f(ua.w) * b2f(ub.w);
#pragma unroll
    for (int m = 32; m >= 1; m >>= 1) s += __shfl_xor(s, m, 64);
    if (lane == 0) out[idx] = s;
}

extern "C" void kernel_launch(void* const* d_in, const int* in_sizes, int n_in,
                              void* d_out, int out_size, void* d_ws, size_t ws_size,
                              hipStream_t stream) {
    const float* x = (const float*)d_in[0];
    const int* ei = (const int*)d_in[1];
    const int* pei = (const int*)d_in[2];
    const int* nei = (const int*)d_in[3];
    const float* W1 = (const float*)d_in[4];
    const float* as1 = (const float*)d_in[5];
    const float* ad1 = (const float*)d_in[6];
    const float* b1 = (const float*)d_in[7];
    const float* W2 = (const float*)d_in[8];
    const float* as2 = (const float*)d_in[9];
    const float* ad2 = (const float*)d_in[10];
    const float* b2 = (const float*)d_in[11];
    float* out = (float*)d_out;

    // ---- workspace layout ----
    unsigned short* h1 = (unsigned short*)d_ws;              // NN*128
    unsigned short* h2 = h1 + (long long)NN * 128;           // NN*256
    unsigned short* z2 = h2 + (long long)NN * 256;           // NN*256
    unsigned short* z1 = z2 + (long long)NN * 256;           // NN*128
    unsigned short* xb = z1 + (long long)NN * 128;           // NN*128
    unsigned short* wp1 = xb + (long long)NN * 128;          // 128*128
    unsigned short* wp2 = wp1 + 128 * 128;                   // 128*256
    float* als1 = (float*)(wp2 + 128 * 256);                 // NN*H1
    float* ald1 = als1 + NN * H1;
    float* als2 = ald1 + NN * H1;                            // NN*H2
    float* ald2 = als2 + NN * H2;
    int* counts = (int*)(ald2 + NN * H2);                    // NN
    int* start = counts + NN;                                // NN+1
    int* cursor = start + NN + 1;                            // NN
    int* bsum = cursor + NN;                                 // 256
    int* csr = bsum + 256;                                   // ET

    const int NB = (NN + 255) / 256;  // 196

    // ---- CSR build ----
    fillint_k<<<NB, 256, 0, stream>>>(counts, NN);
    hist_k<<<(ET + 255) / 256, 256, 0, stream>>>(ei, counts);
    scan1_k<<<NB, 256, 0, stream>>>(counts, bsum);
    scan2_k<<<1, 256, 0, stream>>>(bsum, NB, start);
    scan3_k<<<NB, 256, 0, stream>>>(counts, bsum, start, cursor);
    scatter_k<<<(ET + 255) / 256, 256, 0, stream>>>(ei, cursor, csr);

    // ---- input conversion + weight packing ----
    const int n4 = NN * 128 / 4;
    cvt_k<<<(n4 + 255) / 256, 256, 0, stream>>>((const float4*)x, (ushort4*)xb, n4);
    packW_k<128><<<(2048 + 255) / 256, 256, 0, stream>>>(W1, wp1);
    packW_k<256><<<(4096 + 255) / 256, 256, 0, stream>>>(W2, wp2);

    // ---- conv1 ----
    mfma_gemm_k<128, 2><<<(NN + 63) / 64, 256, 0, stream>>>(xb, wp1, h1);
    al_k<128, H1><<<NN / 4, 256, 0, stream>>>(h1, as1, ad1, als1, ald1);
    gather_k<128, H1, true><<<NN, 256, 0, stream>>>(start, csr, als1, ald1, h1, b1, z1);

    // ---- conv2 ----
    mfma_gemm_k<256, 4><<<(NN + 63) / 64, 256, 0, stream>>>(z1, wp2, h2);
    al_k<256, H2><<<NN / 4, 256, 0, stream>>>(h2, as2, ad2, als2, ald2);
    gather_k<256, H2, false><<<NN, 256, 0, stream>>>(start, csr, als2, ald2, h2, b2, z2);

    // ---- decode ----
    decode_k<<<(2 * E_DEC + 3) / 4, 256, 0, stream>>>(pei, nei, z2, out);
}

// Round 7
// 383.003 us; speedup vs baseline: 1.1839x; 1.1839x over previous
//
#include <hip/hip_runtime.h>
#include <hip/hip_bf16.h>

#define NN 50000
#define EE 800000
#define ET (EE + NN)
#define F_IN 128
#define HID 32
#define H1 4
#define H2 8
#define E_DEC 100000
#define NEG_SLOPE 0.2f

typedef __attribute__((ext_vector_type(8))) short short8;
typedef __attribute__((ext_vector_type(4))) float floatx4;

__device__ __forceinline__ unsigned short f2b(float f) {
    __hip_bfloat16 h = __float2bfloat16(f);
    return *reinterpret_cast<unsigned short*>(&h);
}
__device__ __forceinline__ float b2f(unsigned short u) {
    return __uint_as_float(((unsigned int)u) << 16);
}

// ---------------- zero ints ----------------
__global__ void fillint_k(int* __restrict__ p, int n) {
    int i = blockIdx.x * blockDim.x + threadIdx.x;
    if (i < n) p[i] = 0;
}

// ---------------- CSR build ----------------
__global__ void hist_k(const int* __restrict__ ei, int* __restrict__ counts) {
    int e = blockIdx.x * blockDim.x + threadIdx.x;
    if (e >= ET) return;
    int d = (e < EE) ? ei[EE + e] : e - EE;
    atomicAdd(&counts[d], 1);
}

__global__ void scan1_k(const int* __restrict__ counts, int* __restrict__ bsum) {
    __shared__ int sh[256];
    int t = threadIdx.x;
    int i = blockIdx.x * 256 + t;
    sh[t] = (i < NN) ? counts[i] : 0;
    __syncthreads();
    for (int off = 128; off > 0; off >>= 1) {
        if (t < off) sh[t] += sh[t + off];
        __syncthreads();
    }
    if (t == 0) bsum[blockIdx.x] = sh[0];
}

__global__ void scan2_k(int* __restrict__ bsum, int nb, int* __restrict__ start) {
    __shared__ int sh[256];
    int t = threadIdx.x;
    int v = (t < nb) ? bsum[t] : 0;
    sh[t] = v;
    __syncthreads();
    for (int off = 1; off < 256; off <<= 1) {
        int u = (t >= off) ? sh[t - off] : 0;
        __syncthreads();
        sh[t] += u;
        __syncthreads();
    }
    if (t < nb) bsum[t] = sh[t] - v;
    if (t == 0) start[NN] = ET;
}

__global__ void scan3_k(const int* __restrict__ counts, const int* __restrict__ bsum,
                        int* __restrict__ start, int* __restrict__ cursor) {
    __shared__ int sh[256];
    int t = threadIdx.x;
    int i = blockIdx.x * 256 + t;
    int c = (i < NN) ? counts[i] : 0;
    sh[t] = c;
    __syncthreads();
    for (int off = 1; off < 256; off <<= 1) {
        int u = (t >= off) ? sh[t - off] : 0;
        __syncthreads();
        sh[t] += u;
        __syncthreads();
    }
    int excl = sh[t] - c + bsum[blockIdx.x];
    if (i < NN) {
        start[i] = excl;
        cursor[i] = excl;
    }
}

__global__ void scatter_k(const int* __restrict__ ei, int* __restrict__ cursor,
                          int* __restrict__ csr) {
    int e = blockIdx.x * blockDim.x + threadIdx.x;
    if (e >= ET) return;
    int s, d;
    if (e < EE) { s = ei[e]; d = ei[EE + e]; } else { s = d = e - EE; }
    int slot = atomicAdd(&cursor[d], 1);
    csr[slot] = s;
}

// ---------------- fp32 -> bf16 convert (x) ----------------
__global__ void cvt_k(const float4* __restrict__ X, ushort4* __restrict__ Xb, int n4) {
    int i = blockIdx.x * blockDim.x + threadIdx.x;
    if (i >= n4) return;
    float4 v = X[i];
    ushort4 o;
    o.x = f2b(v.x);
    o.y = f2b(v.y);
    o.z = f2b(v.z);
    o.w = f2b(v.w);
    Xb[i] = o;
}

// ---------------- pack W into MFMA B-fragment layout ----------------
template <int OUT>
__global__ void packW_k(const float* __restrict__ W, unsigned short* __restrict__ Wp) {
    const int total = (OUT / 16) * 4 * 64;
    int id = blockIdx.x * 256 + threadIdx.x;
    if (id >= total) return;
    const int col = ((id >> 8) << 4) + (id & 15);
    const int k0 = ((id >> 6) & 3) * 32 + ((id >> 4) & 3) * 8;
    ushort4 lo, hi;
    lo.x = f2b(W[(k0 + 0) * OUT + col]);
    lo.y = f2b(W[(k0 + 1) * OUT + col]);
    lo.z = f2b(W[(k0 + 2) * OUT + col]);
    lo.w = f2b(W[(k0 + 3) * OUT + col]);
    hi.x = f2b(W[(k0 + 4) * OUT + col]);
    hi.y = f2b(W[(k0 + 5) * OUT + col]);
    hi.z = f2b(W[(k0 + 6) * OUT + col]);
    hi.w = f2b(W[(k0 + 7) * OUT + col]);
    ((ushort4*)Wp)[id * 2] = lo;
    ((ushort4*)Wp)[id * 2 + 1] = hi;
}

// ---------------- MFMA GEMM: H[M,OUT] = Xb[M,128] @ W, bf16 in/out, fp32 acc ------
template <int OUT, int CT>
__global__ void mfma_gemm_k(const unsigned short* __restrict__ Xb,
                            const unsigned short* __restrict__ Wp,
                            unsigned short* __restrict__ Hout) {
    const int wave = threadIdx.x >> 6;
    const int lane = threadIdx.x & 63;
    const int quad = lane >> 4;
    const int rl = lane & 15;
    const int r0 = blockIdx.x * 64;
    floatx4 acc[4][CT];
#pragma unroll
    for (int rt = 0; rt < 4; ++rt)
#pragma unroll
        for (int ct = 0; ct < CT; ++ct) acc[rt][ct] = {0.f, 0.f, 0.f, 0.f};

#pragma unroll
    for (int ks = 0; ks < 4; ++ks) {
        short8 a[4];
#pragma unroll
        for (int rt = 0; rt < 4; ++rt) {
            int row = r0 + rt * 16 + rl;
            row = row < NN ? row : NN - 1;
            a[rt] = *(const short8*)(Xb + (long long)row * 128 + ks * 32 + quad * 8);
        }
#pragma unroll
        for (int ct = 0; ct < CT; ++ct) {
            const int ctg = wave * CT + ct;
            const short8 b = *(const short8*)(Wp + (((ctg * 4 + ks) * 64 + lane) << 3));
#pragma unroll
            for (int rt = 0; rt < 4; ++rt)
                acc[rt][ct] = __builtin_amdgcn_mfma_f32_16x16x32_bf16(a[rt], b, acc[rt][ct], 0, 0, 0);
        }
    }
#pragma unroll
    for (int rt = 0; rt < 4; ++rt) {
        const int rowbase = r0 + rt * 16 + quad * 4;
#pragma unroll
        for (int ct = 0; ct < CT; ++ct) {
            const int col = (wave * CT + ct) * 16 + rl;
#pragma unroll
            for (int r = 0; r < 4; ++r) {
                const int row = rowbase + r;
                if (row < NN) Hout[(long long)row * OUT + col] = f2b(acc[rt][ct][r]);
            }
        }
    }
}

// ---------------- attention logit terms from h (bf16) ----------------
template <int OUT, int H>
__global__ void al_k(const unsigned short* __restrict__ Hb, const float* __restrict__ a_src,
                     const float* __restrict__ a_dst, float* __restrict__ als,
                     float* __restrict__ ald) {
    const int wave = threadIdx.x >> 6;
    const int lane = threadIdx.x & 63;
    const int row = blockIdx.x * 4 + wave;
    const int CPL = OUT / 64;
    const int G = 32 / CPL;
    const int c0 = lane * CPL;
    const int hd = c0 >> 5;
    float ps = 0.f, pd = 0.f;
#pragma unroll
    for (int j = 0; j < CPL; ++j) {
        const float hv = b2f(Hb[(long long)row * OUT + c0 + j]);
        const int cc = hd * 32 + ((c0 + j) & 31);
        ps += hv * a_src[cc];
        pd += hv * a_dst[cc];
    }
#pragma unroll
    for (int m = G / 2; m >= 1; m >>= 1) {
        ps += __shfl_xor(ps, m, 64);
        pd += __shfl_xor(pd, m, 64);
    }
    if ((lane & (G - 1)) == 0) {
        als[row * H + hd] = ps;
        ald[row * H + hd] = pd;
    }
}

// ---------------- CSR gather v3: one wave per node, ushort4/lane, 4-edge unroll ----
// LPR lanes cover one row (4 ch each). OUT=256: EPW=1 slot; OUT=128: 2 slots,
// combined by shfl_xor(32) at the end. No LDS, no syncthreads.
template <int OUT, int H, bool RELU>
__global__ void gather_k(const int* __restrict__ start, const int* __restrict__ csr,
                         const float* __restrict__ als, const float* __restrict__ ald,
                         const unsigned short* __restrict__ Hin,
                         const float* __restrict__ bias, unsigned short* __restrict__ outp) {
    constexpr int LPR = OUT / 4;           // 64 (OUT=256) or 32 (OUT=128)
    constexpr int EPW = 64 / LPR;          // 1 or 2
    const int d = blockIdx.x;
    const int lane = threadIdx.x;          // blockDim = 64
    const int cl = lane & (LPR - 1);
    const int slot = lane >> (LPR == 64 ? 6 : 5);  // 0, or 0/1
    const int hd = cl >> 3;
    const int beg = start[d], end = start[d + 1];
    const float aldd = ald[d * H + hd];
    float a0 = 0.f, a1 = 0.f, a2 = 0.f, a3 = 0.f, den = 0.f;
    int i = beg + slot;
    for (; i + 3 * EPW < end; i += 4 * EPW) {
        const int s0 = csr[i], s1 = csr[i + EPW], s2 = csr[i + 2 * EPW], s3 = csr[i + 3 * EPW];
        float l0 = als[s0 * H + hd] + aldd;
        float l1 = als[s1 * H + hd] + aldd;
        float l2 = als[s2 * H + hd] + aldd;
        float l3 = als[s3 * H + hd] + aldd;
        const ushort4 h0 = *(const ushort4*)(Hin + (long long)s0 * OUT + cl * 4);
        const ushort4 h1 = *(const ushort4*)(Hin + (long long)s1 * OUT + cl * 4);
        const ushort4 h2 = *(const ushort4*)(Hin + (long long)s2 * OUT + cl * 4);
        const ushort4 h3 = *(const ushort4*)(Hin + (long long)s3 * OUT + cl * 4);
        l0 = l0 > 0.f ? l0 : NEG_SLOPE * l0;
        l1 = l1 > 0.f ? l1 : NEG_SLOPE * l1;
        l2 = l2 > 0.f ? l2 : NEG_SLOPE * l2;
        l3 = l3 > 0.f ? l3 : NEG_SLOPE * l3;
        const float w0 = __expf(l0), w1 = __expf(l1), w2 = __expf(l2), w3 = __expf(l3);
        den += (w0 + w1) + (w2 + w3);
        a0 += w0 * b2f(h0.x) + w1 * b2f(h1.x) + w2 * b2f(h2.x) + w3 * b2f(h3.x);
        a1 += w0 * b2f(h0.y) + w1 * b2f(h1.y) + w2 * b2f(h2.y) + w3 * b2f(h3.y);
        a2 += w0 * b2f(h0.z) + w1 * b2f(h1.z) + w2 * b2f(h2.z) + w3 * b2f(h3.z);
        a3 += w0 * b2f(h0.w) + w1 * b2f(h1.w) + w2 * b2f(h2.w) + w3 * b2f(h3.w);
    }
    for (; i < end; i += EPW) {
        const int s = csr[i];
        float lg = als[s * H + hd] + aldd;
        lg = lg > 0.f ? lg : NEG_SLOPE * lg;
        const float w = __expf(lg);
        const ushort4 hv = *(const ushort4*)(Hin + (long long)s * OUT + cl * 4);
        den += w;
        a0 += w * b2f(hv.x);
        a1 += w * b2f(hv.y);
        a2 += w * b2f(hv.z);
        a3 += w * b2f(hv.w);
    }
    if (EPW == 2) {
        a0 += __shfl_xor(a0, 32, 64);
        a1 += __shfl_xor(a1, 32, 64);
        a2 += __shfl_xor(a2, 32, 64);
        a3 += __shfl_xor(a3, 32, 64);
        den += __shfl_xor(den, 32, 64);
    }
    if (lane < LPR) {
        const float inv = 1.f / (den + 1e-16f);
        const int c0 = cl * 4;
        float v0 = a0 * inv + bias[c0];
        float v1 = a1 * inv + bias[c0 + 1];
        float v2 = a2 * inv + bias[c0 + 2];
        float v3 = a3 * inv + bias[c0 + 3];
        if (RELU) {
            v0 = v0 > 0.f ? v0 : 0.f;
            v1 = v1 > 0.f ? v1 : 0.f;
            v2 = v2 > 0.f ? v2 : 0.f;
            v3 = v3 > 0.f ? v3 : 0.f;
        }
        ushort4 o;
        o.x = f2b(v0);
        o.y = f2b(v1);
        o.z = f2b(v2);
        o.w = f2b(v3);
        *(ushort4*)(outp + (long long)d * OUT + c0) = o;
    }
}

// ---------------- decode: logits = sum(z2[a]*z2[b]), z2 in bf16, ushort4/lane ------
__global__ void decode_k(const int* __restrict__ pei, const int* __restrict__ nei,
                         const unsigned short* __restrict__ z2, float* __restrict__ out) {
    const int w = threadIdx.x >> 6, lane = threadIdx.x & 63;
    const int idx = blockIdx.x * 4 + w;
    if (idx >= 2 * E_DEC) return;
    int a, b;
    if (idx < E_DEC) {
        a = pei[idx];
        b = pei[E_DEC + idx];
    } else {
        const int j = idx - E_DEC;
        a = nei[j];
        b = nei[E_DEC + j];
    }
    const ushort4 ua = *(const ushort4*)(z2 + (long long)a * 256 + lane * 4);
    const ushort4 ub = *(const ushort4*)(z2 + (long long)b * 256 + lane * 4);
    float s = b2f(ua.x) * b2f(ub.x) + b2f(ua.y) * b2f(ub.y) +
              b2f(ua.z) * b2f(ub.z) + b2f(ua.w) * b2f(ub.w);
#pragma unroll
    for (int m = 32; m >= 1; m >>= 1) s += __shfl_xor(s, m, 64);
    if (lane == 0) out[idx] = s;
}

extern "C" void kernel_launch(void* const* d_in, const int* in_sizes, int n_in,
                              void* d_out, int out_size, void* d_ws, size_t ws_size,
                              hipStream_t stream) {
    const float* x = (const float*)d_in[0];
    const int* ei = (const int*)d_in[1];
    const int* pei = (const int*)d_in[2];
    const int* nei = (const int*)d_in[3];
    const float* W1 = (const float*)d_in[4];
    const float* as1 = (const float*)d_in[5];
    const float* ad1 = (const float*)d_in[6];
    const float* b1 = (const float*)d_in[7];
    const float* W2 = (const float*)d_in[8];
    const float* as2 = (const float*)d_in[9];
    const float* ad2 = (const float*)d_in[10];
    const float* b2 = (const float*)d_in[11];
    float* out = (float*)d_out;

    // ---- workspace layout ----
    unsigned short* h1 = (unsigned short*)d_ws;              // NN*128
    unsigned short* h2 = h1 + (long long)NN * 128;           // NN*256
    unsigned short* z2 = h2 + (long long)NN * 256;           // NN*256
    unsigned short* z1 = z2 + (long long)NN * 256;           // NN*128
    unsigned short* xb = z1 + (long long)NN * 128;           // NN*128
    unsigned short* wp1 = xb + (long long)NN * 128;          // 128*128
    unsigned short* wp2 = wp1 + 128 * 128;                   // 128*256
    float* als1 = (float*)(wp2 + 128 * 256);                 // NN*H1
    float* ald1 = als1 + NN * H1;
    float* als2 = ald1 + NN * H1;                            // NN*H2
    float* ald2 = als2 + NN * H2;
    int* counts = (int*)(ald2 + NN * H2);                    // NN
    int* start = counts + NN;                                // NN+1
    int* cursor = start + NN + 1;                            // NN
    int* bsum = cursor + NN;                                 // 256
    int* csr = bsum + 256;                                   // ET

    const int NB = (NN + 255) / 256;  // 196

    // ---- CSR build ----
    fillint_k<<<NB, 256, 0, stream>>>(counts, NN);
    hist_k<<<(ET + 255) / 256, 256, 0, stream>>>(ei, counts);
    scan1_k<<<NB, 256, 0, stream>>>(counts, bsum);
    scan2_k<<<1, 256, 0, stream>>>(bsum, NB, start);
    scan3_k<<<NB, 256, 0, stream>>>(counts, bsum, start, cursor);
    scatter_k<<<(ET + 255) / 256, 256, 0, stream>>>(ei, cursor, csr);

    // ---- input conversion + weight packing ----
    const int n4 = NN * 128 / 4;
    cvt_k<<<(n4 + 255) / 256, 256, 0, stream>>>((const float4*)x, (ushort4*)xb, n4);
    packW_k<128><<<(2048 + 255) / 256, 256, 0, stream>>>(W1, wp1);
    packW_k<256><<<(4096 + 255) / 256, 256, 0, stream>>>(W2, wp2);

    // ---- conv1 ----
    mfma_gemm_k<128, 2><<<(NN + 63) / 64, 256, 0, stream>>>(xb, wp1, h1);
    al_k<128, H1><<<NN / 4, 256, 0, stream>>>(h1, as1, ad1, als1, ald1);
    gather_k<128, H1, true><<<NN, 64, 0, stream>>>(start, csr, als1, ald1, h1, b1, z1);

    // ---- conv2 ----
    mfma_gemm_k<256, 4><<<(NN + 63) / 64, 256, 0, stream>>>(z1, wp2, h2);
    al_k<256, H2><<<NN / 4, 256, 0, stream>>>(h2, as2, ad2, als2, ald2);
    gather_k<256, H2, false><<<NN, 64, 0, stream>>>(start, csr, als2, ald2, h2, b2, z2);

    // ---- decode ----
    decode_k<<<(2 * E_DEC + 3) / 4, 256, 0, stream>>>(pei, nei, z2, out);
}

// Round 8
// 380.371 us; speedup vs baseline: 1.1920x; 1.0069x over previous
//
#include <hip/hip_runtime.h>
#include <hip/hip_bf16.h>

#define NN 50000
#define EE 800000
#define ET (EE + NN)
#define F_IN 128
#define HID 32
#define H1 4
#define H2 8
#define E_DEC 100000
#define NEG_SLOPE 0.2f

typedef __attribute__((ext_vector_type(8))) short short8;
typedef __attribute__((ext_vector_type(4))) float floatx4;

__device__ __forceinline__ unsigned short f2b(float f) {
    __hip_bfloat16 h = __float2bfloat16(f);
    return *reinterpret_cast<unsigned short*>(&h);
}
__device__ __forceinline__ float b2f(unsigned short u) {
    return __uint_as_float(((unsigned int)u) << 16);
}

// ---------------- zero ints ----------------
__global__ void fillint_k(int* __restrict__ p, int n) {
    int i = blockIdx.x * blockDim.x + threadIdx.x;
    if (i < n) p[i] = 0;
}

// ---------------- CSR build ----------------
__global__ void hist_k(const int* __restrict__ ei, int* __restrict__ counts) {
    int e = blockIdx.x * blockDim.x + threadIdx.x;
    if (e >= ET) return;
    int d = (e < EE) ? ei[EE + e] : e - EE;
    atomicAdd(&counts[d], 1);
}

__global__ void scan1_k(const int* __restrict__ counts, int* __restrict__ bsum) {
    __shared__ int sh[256];
    int t = threadIdx.x;
    int i = blockIdx.x * 256 + t;
    sh[t] = (i < NN) ? counts[i] : 0;
    __syncthreads();
    for (int off = 128; off > 0; off >>= 1) {
        if (t < off) sh[t] += sh[t + off];
        __syncthreads();
    }
    if (t == 0) bsum[blockIdx.x] = sh[0];
}

__global__ void scan2_k(int* __restrict__ bsum, int nb, int* __restrict__ start) {
    __shared__ int sh[256];
    int t = threadIdx.x;
    int v = (t < nb) ? bsum[t] : 0;
    sh[t] = v;
    __syncthreads();
    for (int off = 1; off < 256; off <<= 1) {
        int u = (t >= off) ? sh[t - off] : 0;
        __syncthreads();
        sh[t] += u;
        __syncthreads();
    }
    if (t < nb) bsum[t] = sh[t] - v;
    if (t == 0) start[NN] = ET;
}

__global__ void scan3_k(const int* __restrict__ counts, const int* __restrict__ bsum,
                        int* __restrict__ start, int* __restrict__ cursor) {
    __shared__ int sh[256];
    int t = threadIdx.x;
    int i = blockIdx.x * 256 + t;
    int c = (i < NN) ? counts[i] : 0;
    sh[t] = c;
    __syncthreads();
    for (int off = 1; off < 256; off <<= 1) {
        int u = (t >= off) ? sh[t - off] : 0;
        __syncthreads();
        sh[t] += u;
        __syncthreads();
    }
    int excl = sh[t] - c + bsum[blockIdx.x];
    if (i < NN) {
        start[i] = excl;
        cursor[i] = excl;
    }
}

__global__ void scatter_k(const int* __restrict__ ei, int* __restrict__ cursor,
                          int* __restrict__ csr) {
    int e = blockIdx.x * blockDim.x + threadIdx.x;
    if (e >= ET) return;
    int s, d;
    if (e < EE) { s = ei[e]; d = ei[EE + e]; } else { s = d = e - EE; }
    int slot = atomicAdd(&cursor[d], 1);
    csr[slot] = s;
}

// ---------------- pack W into MFMA B-fragment layout ----------------
template <int OUT>
__global__ void packW_k(const float* __restrict__ W, unsigned short* __restrict__ Wp) {
    const int total = (OUT / 16) * 4 * 64;
    int id = blockIdx.x * 256 + threadIdx.x;
    if (id >= total) return;
    const int col = ((id >> 8) << 4) + (id & 15);
    const int k0 = ((id >> 6) & 3) * 32 + ((id >> 4) & 3) * 8;
    ushort4 lo, hi;
    lo.x = f2b(W[(k0 + 0) * OUT + col]);
    lo.y = f2b(W[(k0 + 1) * OUT + col]);
    lo.z = f2b(W[(k0 + 2) * OUT + col]);
    lo.w = f2b(W[(k0 + 3) * OUT + col]);
    hi.x = f2b(W[(k0 + 4) * OUT + col]);
    hi.y = f2b(W[(k0 + 5) * OUT + col]);
    hi.z = f2b(W[(k0 + 6) * OUT + col]);
    hi.w = f2b(W[(k0 + 7) * OUT + col]);
    ((ushort4*)Wp)[id * 2] = lo;
    ((ushort4*)Wp)[id * 2 + 1] = hi;
}

// ---------------- MFMA GEMM + fused al epilogue ----------------
// H[M,OUT] = X[M,128] @ W (bf16 out, fp32 acc). If F32IN, X is fp32 and
// converted in-register. als/ald computed from the fp32 accumulators:
// wave w owns cols [w*CT*16, ...), i.e. CT/2 whole heads.
template <int OUT, int H, int CT, bool F32IN>
__global__ void mfma_gemm_k(const void* __restrict__ Xin,
                            const unsigned short* __restrict__ Wp,
                            const float* __restrict__ a_src, const float* __restrict__ a_dst,
                            unsigned short* __restrict__ Hout,
                            float* __restrict__ als, float* __restrict__ ald) {
    const int wave = threadIdx.x >> 6;
    const int lane = threadIdx.x & 63;
    const int quad = lane >> 4;
    const int rl = lane & 15;
    const int r0 = blockIdx.x * 64;
    floatx4 acc[4][CT];
#pragma unroll
    for (int rt = 0; rt < 4; ++rt)
#pragma unroll
        for (int ct = 0; ct < CT; ++ct) acc[rt][ct] = {0.f, 0.f, 0.f, 0.f};

#pragma unroll
    for (int ks = 0; ks < 4; ++ks) {
        short8 a[4];
#pragma unroll
        for (int rt = 0; rt < 4; ++rt) {
            int row = r0 + rt * 16 + rl;
            row = row < NN ? row : NN - 1;
            if (F32IN) {
                const float4* xp =
                    (const float4*)((const float*)Xin + (long long)row * 128 + ks * 32 + quad * 8);
                const float4 v0 = xp[0];
                const float4 v1 = xp[1];
                short8 t;
                t[0] = (short)f2b(v0.x);
                t[1] = (short)f2b(v0.y);
                t[2] = (short)f2b(v0.z);
                t[3] = (short)f2b(v0.w);
                t[4] = (short)f2b(v1.x);
                t[5] = (short)f2b(v1.y);
                t[6] = (short)f2b(v1.z);
                t[7] = (short)f2b(v1.w);
                a[rt] = t;
            } else {
                a[rt] = *(const short8*)((const unsigned short*)Xin +
                                         (long long)row * 128 + ks * 32 + quad * 8);
            }
        }
#pragma unroll
        for (int ct = 0; ct < CT; ++ct) {
            const int ctg = wave * CT + ct;
            const short8 b = *(const short8*)(Wp + (((ctg * 4 + ks) * 64 + lane) << 3));
#pragma unroll
            for (int rt = 0; rt < 4; ++rt)
                acc[rt][ct] = __builtin_amdgcn_mfma_f32_16x16x32_bf16(a[rt], b, acc[rt][ct], 0, 0, 0);
        }
    }
    // ---- write h ----
#pragma unroll
    for (int rt = 0; rt < 4; ++rt) {
        const int rowbase = r0 + rt * 16 + quad * 4;
#pragma unroll
        for (int ct = 0; ct < CT; ++ct) {
            const int col = (wave * CT + ct) * 16 + rl;
#pragma unroll
            for (int r = 0; r < 4; ++r) {
                const int row = rowbase + r;
                if (row < NN) Hout[(long long)row * OUT + col] = f2b(acc[rt][ct][r]);
            }
        }
    }
    // ---- fused al: reduce acc over the 32 cols of each head ----
    float asv[CT], adv[CT];
#pragma unroll
    for (int ct = 0; ct < CT; ++ct) {
        const int col = (wave * CT + ct) * 16 + rl;
        asv[ct] = a_src[col];
        adv[ct] = a_dst[col];
    }
#pragma unroll
    for (int rt = 0; rt < 4; ++rt) {
#pragma unroll
        for (int r = 0; r < 4; ++r) {
            const int row = r0 + rt * 16 + quad * 4 + r;
            float ps[CT / 2], pd[CT / 2];
#pragma unroll
            for (int hh = 0; hh < CT / 2; ++hh) {
                ps[hh] = acc[rt][2 * hh][r] * asv[2 * hh] + acc[rt][2 * hh + 1][r] * asv[2 * hh + 1];
                pd[hh] = acc[rt][2 * hh][r] * adv[2 * hh] + acc[rt][2 * hh + 1][r] * adv[2 * hh + 1];
#pragma unroll
                for (int m = 8; m >= 1; m >>= 1) {
                    ps[hh] += __shfl_xor(ps[hh], m, 64);
                    pd[hh] += __shfl_xor(pd[hh], m, 64);
                }
            }
            if (rl == 0 && row < NN) {
#pragma unroll
                for (int hh = 0; hh < CT / 2; ++hh) {
                    const int hd = wave * (CT / 2) + hh;
                    als[row * H + hd] = ps[hh];
                    ald[row * H + hd] = pd[hh];
                }
            }
        }
    }
}

// ---------------- CSR gather: one wave per node, ushort4/lane, 4-edge unroll ----
template <int OUT, int H, bool RELU>
__global__ void gather_k(const int* __restrict__ start, const int* __restrict__ csr,
                         const float* __restrict__ als, const float* __restrict__ ald,
                         const unsigned short* __restrict__ Hin,
                         const float* __restrict__ bias, unsigned short* __restrict__ outp) {
    constexpr int LPR = OUT / 4;           // 64 (OUT=256) or 32 (OUT=128)
    constexpr int EPW = 64 / LPR;          // 1 or 2
    const int d = blockIdx.x;
    const int lane = threadIdx.x;          // blockDim = 64
    const int cl = lane & (LPR - 1);
    const int slot = lane >> (LPR == 64 ? 6 : 5);
    const int hd = cl >> 3;
    const int beg = start[d], end = start[d + 1];
    const float aldd = ald[d * H + hd];
    float a0 = 0.f, a1 = 0.f, a2 = 0.f, a3 = 0.f, den = 0.f;
    int i = beg + slot;
    for (; i + 3 * EPW < end; i += 4 * EPW) {
        const int s0 = csr[i], s1 = csr[i + EPW], s2 = csr[i + 2 * EPW], s3 = csr[i + 3 * EPW];
        float l0 = als[s0 * H + hd] + aldd;
        float l1 = als[s1 * H + hd] + aldd;
        float l2 = als[s2 * H + hd] + aldd;
        float l3 = als[s3 * H + hd] + aldd;
        const ushort4 h0 = *(const ushort4*)(Hin + (long long)s0 * OUT + cl * 4);
        const ushort4 h1 = *(const ushort4*)(Hin + (long long)s1 * OUT + cl * 4);
        const ushort4 h2 = *(const ushort4*)(Hin + (long long)s2 * OUT + cl * 4);
        const ushort4 h3 = *(const ushort4*)(Hin + (long long)s3 * OUT + cl * 4);
        l0 = l0 > 0.f ? l0 : NEG_SLOPE * l0;
        l1 = l1 > 0.f ? l1 : NEG_SLOPE * l1;
        l2 = l2 > 0.f ? l2 : NEG_SLOPE * l2;
        l3 = l3 > 0.f ? l3 : NEG_SLOPE * l3;
        const float w0 = __expf(l0), w1 = __expf(l1), w2 = __expf(l2), w3 = __expf(l3);
        den += (w0 + w1) + (w2 + w3);
        a0 += w0 * b2f(h0.x) + w1 * b2f(h1.x) + w2 * b2f(h2.x) + w3 * b2f(h3.x);
        a1 += w0 * b2f(h0.y) + w1 * b2f(h1.y) + w2 * b2f(h2.y) + w3 * b2f(h3.y);
        a2 += w0 * b2f(h0.z) + w1 * b2f(h1.z) + w2 * b2f(h2.z) + w3 * b2f(h3.z);
        a3 += w0 * b2f(h0.w) + w1 * b2f(h1.w) + w2 * b2f(h2.w) + w3 * b2f(h3.w);
    }
    for (; i < end; i += EPW) {
        const int s = csr[i];
        float lg = als[s * H + hd] + aldd;
        lg = lg > 0.f ? lg : NEG_SLOPE * lg;
        const float w = __expf(lg);
        const ushort4 hv = *(const ushort4*)(Hin + (long long)s * OUT + cl * 4);
        den += w;
        a0 += w * b2f(hv.x);
        a1 += w * b2f(hv.y);
        a2 += w * b2f(hv.z);
        a3 += w * b2f(hv.w);
    }
    if (EPW == 2) {
        a0 += __shfl_xor(a0, 32, 64);
        a1 += __shfl_xor(a1, 32, 64);
        a2 += __shfl_xor(a2, 32, 64);
        a3 += __shfl_xor(a3, 32, 64);
        den += __shfl_xor(den, 32, 64);
    }
    if (lane < LPR) {
        const float inv = 1.f / (den + 1e-16f);
        const int c0 = cl * 4;
        float v0 = a0 * inv + bias[c0];
        float v1 = a1 * inv + bias[c0 + 1];
        float v2 = a2 * inv + bias[c0 + 2];
        float v3 = a3 * inv + bias[c0 + 3];
        if (RELU) {
            v0 = v0 > 0.f ? v0 : 0.f;
            v1 = v1 > 0.f ? v1 : 0.f;
            v2 = v2 > 0.f ? v2 : 0.f;
            v3 = v3 > 0.f ? v3 : 0.f;
        }
        ushort4 o;
        o.x = f2b(v0);
        o.y = f2b(v1);
        o.z = f2b(v2);
        o.w = f2b(v3);
        *(ushort4*)(outp + (long long)d * OUT + c0) = o;
    }
}

// ---------------- decode: logits = sum(z2[a]*z2[b]), z2 in bf16, ushort4/lane ------
__global__ void decode_k(const int* __restrict__ pei, const int* __restrict__ nei,
                         const unsigned short* __restrict__ z2, float* __restrict__ out) {
    const int w = threadIdx.x >> 6, lane = threadIdx.x & 63;
    const int idx = blockIdx.x * 4 + w;
    if (idx >= 2 * E_DEC) return;
    int a, b;
    if (idx < E_DEC) {
        a = pei[idx];
        b = pei[E_DEC + idx];
    } else {
        const int j = idx - E_DEC;
        a = nei[j];
        b = nei[E_DEC + j];
    }
    const ushort4 ua = *(const ushort4*)(z2 + (long long)a * 256 + lane * 4);
    const ushort4 ub = *(const ushort4*)(z2 + (long long)b * 256 + lane * 4);
    float s = b2f(ua.x) * b2f(ub.x) + b2f(ua.y) * b2f(ub.y) +
              b2f(ua.z) * b2f(ub.z) + b2f(ua.w) * b2f(ub.w);
#pragma unroll
    for (int m = 32; m >= 1; m >>= 1) s += __shfl_xor(s, m, 64);
    if (lane == 0) out[idx] = s;
}

extern "C" void kernel_launch(void* const* d_in, const int* in_sizes, int n_in,
                              void* d_out, int out_size, void* d_ws, size_t ws_size,
                              hipStream_t stream) {
    const float* x = (const float*)d_in[0];
    const int* ei = (const int*)d_in[1];
    const int* pei = (const int*)d_in[2];
    const int* nei = (const int*)d_in[3];
    const float* W1 = (const float*)d_in[4];
    const float* as1 = (const float*)d_in[5];
    const float* ad1 = (const float*)d_in[6];
    const float* b1 = (const float*)d_in[7];
    const float* W2 = (const float*)d_in[8];
    const float* as2 = (const float*)d_in[9];
    const float* ad2 = (const float*)d_in[10];
    const float* b2 = (const float*)d_in[11];
    float* out = (float*)d_out;

    // ---- workspace layout ----
    unsigned short* h1 = (unsigned short*)d_ws;              // NN*128
    unsigned short* h2 = h1 + (long long)NN * 128;           // NN*256
    unsigned short* z2 = h2 + (long long)NN * 256;           // NN*256
    unsigned short* z1 = z2 + (long long)NN * 256;           // NN*128
    unsigned short* wp1 = z1 + (long long)NN * 128;          // 128*128
    unsigned short* wp2 = wp1 + 128 * 128;                   // 128*256
    float* als1 = (float*)(wp2 + 128 * 256);                 // NN*H1
    float* ald1 = als1 + NN * H1;
    float* als2 = ald1 + NN * H1;                            // NN*H2
    float* ald2 = als2 + NN * H2;
    int* counts = (int*)(ald2 + NN * H2);                    // NN
    int* start = counts + NN;                                // NN+1
    int* cursor = start + NN + 1;                            // NN
    int* bsum = cursor + NN;                                 // 256
    int* csr = bsum + 256;                                   // ET

    const int NB = (NN + 255) / 256;  // 196

    // ---- CSR build ----
    fillint_k<<<NB, 256, 0, stream>>>(counts, NN);
    hist_k<<<(ET + 255) / 256, 256, 0, stream>>>(ei, counts);
    scan1_k<<<NB, 256, 0, stream>>>(counts, bsum);
    scan2_k<<<1, 256, 0, stream>>>(bsum, NB, start);
    scan3_k<<<NB, 256, 0, stream>>>(counts, bsum, start, cursor);
    scatter_k<<<(ET + 255) / 256, 256, 0, stream>>>(ei, cursor, csr);

    // ---- weight packing ----
    packW_k<128><<<(2048 + 255) / 256, 256, 0, stream>>>(W1, wp1);
    packW_k<256><<<(4096 + 255) / 256, 256, 0, stream>>>(W2, wp2);

    // ---- conv1: GEMM (fp32 in, fused cvt + al) -> gather ----
    mfma_gemm_k<128, H1, 2, true><<<(NN + 63) / 64, 256, 0, stream>>>(
        x, wp1, as1, ad1, h1, als1, ald1);
    gather_k<128, H1, true><<<NN, 64, 0, stream>>>(start, csr, als1, ald1, h1, b1, z1);

    // ---- conv2: GEMM (bf16 in, fused al) -> gather ----
    mfma_gemm_k<256, H2, 4, false><<<(NN + 63) / 64, 256, 0, stream>>>(
        z1, wp2, as2, ad2, h2, als2, ald2);
    gather_k<256, H2, false><<<NN, 64, 0, stream>>>(start, csr, als2, ald2, h2, b2, z2);

    // ---- decode ----
    decode_k<<<(2 * E_DEC + 3) / 4, 256, 0, stream>>>(pei, nei, z2, out);
}